// Round 9
// baseline (98.830 us; speedup 1.0000x reference)
//
#include <hip/hip_runtime.h>
#include <hip/hip_fp16.h>

#define NQ 12
#define DEPTH 8
#define NCLASS 10
#define BATCH 4096
#define LSTRIDE 68   // LDS row stride in DWORDS (272 B; 16B-aligned rows; bank phase 4l -> <=2-way)
#define WPB 2        // waves per block; 2 samples/wave; LDS = 2*64*68*4 = 34816 B

// ---------------------------------------------------------------------------
// One wave per TWO samples; amplitude pair packed as __half2 in v[64] dwords.
// Frame A: qubit q in 0..5  <-> lane bit (5-q);  q in 6..11 <-> reg bit (11-q)
// Frame B: qubit q in 0..5  <-> reg  bit (5-q);  q in 6..11 <-> lane bit (11-q)
// R9: identical ops to R8, software-pipelined program order:
//   - RT reads issued as (r, r+32) pairs fused with the mask-32 shear
//     (hfun(r+32) = hfun(r)^0x30, same parity -> same column base)
//   - masks 2,1 done per-quad, immediately followed by that quad's b128
//     staging write (incl. next layer's RT1 write across the layer boundary)
// Shears use tan-half-angle form; global cos product deferred to epilogue.
// All DS intra-wave (private region per wave, DS in-order) -> no barriers.
// ---------------------------------------------------------------------------

__device__ __forceinline__ uint32_t h2u(__half2 x) { return __builtin_bit_cast(uint32_t, x); }
__device__ __forceinline__ __half2 u2h(uint32_t x) { return __builtin_bit_cast(__half2, x); }

__device__ constexpr int hfun(int r) {  // src row (old lane) for RT1 output reg r
    const int rb5 = (r >> 5) & 1, rb4 = (r >> 4) & 1, rb3 = (r >> 3) & 1;
    const int rb2 = (r >> 2) & 1, rb1 = (r >> 1) & 1, rb0 = r & 1;
    const int c0 = rb5;
    const int c1 = rb4 ^ rb5;
    const int c2 = rb3 ^ rb4;
    const int c3 = rb2 ^ rb3 ^ rb4;
    const int c4 = rb1 ^ rb2;
    const int c5 = rb0 ^ rb1 ^ rb2;
    return (c0 << 5) | (c1 << 4) | (c2 << 3) | (c3 << 2) | (c4 << 1) | c5;
}

// shear pair: a' = a - t*b ; b' = b + t*a
__device__ __forceinline__ void spair(uint32_t& a_, uint32_t& b_, __half2 Tp, __half2 Tn) {
    const __half2 a = u2h(a_), b = u2h(b_);
    a_ = h2u(__hfma2(Tn, b, a));
    b_ = h2u(__hfma2(Tp, a, b));
}

template <int M>
__device__ __forceinline__ void shearv(uint32_t (&v)[64], __half2 Tp, __half2 Tn) {
#pragma unroll
    for (int r = 0; r < 64; ++r) {
        if (r & M) continue;
        spair(v[r], v[r | M], Tp, Tn);
    }
}

__global__ __launch_bounds__(WPB * 64) void vqc_kernel(const float* __restrict__ X,
                                                       const float* __restrict__ W,
                                                       float* __restrict__ out) {
    __shared__ __align__(16) uint32_t lds[WPB * 64 * LSTRIDE];

    const int lane = threadIdx.x & 63;
    const int wid  = threadIdx.x >> 6;
    const int gw   = blockIdx.x * WPB + wid;   // global wave id
    const int s0   = 2 * gw, s1 = s0 + 1;      // the two samples
    const int l    = lane;

    uint32_t* Wb   = &lds[wid * 64 * LSTRIDE];
    uint32_t* wrow = &Wb[l * LSTRIDE];                 // staging write base (16B aligned)
    const int G = l ^ (l >> 1) ^ ((l >> 2) & 5);       // RT1 src col (lane-local CNOTs folded)
    const uint32_t* colA = &Wb[G];                     // r even (q5=0)
    const uint32_t* colB = &Wb[G ^ 0x30];              // r odd  (q5=1): CNOT(5,6) col flip
    const uint32_t* rT2  = &Wb[l];                     // RT2 read base

    // ---- data encoding: product state for both samples, frame A ----
    float cx0[NQ], sx0[NQ], cx1[NQ], sx1[NQ];
#pragma unroll
    for (int q = 0; q < NQ; ++q) {
        __sincosf(0.5f * X[s0 * NQ + q] + 0.78539816339744831f, &sx0[q], &cx0[q]);
        __sincosf(0.5f * X[s1 * NQ + q] + 0.78539816339744831f, &sx1[q], &cx1[q]);
    }
    float P0 = 1.0f, P1 = 1.0f;
#pragma unroll
    for (int q = 0; q < 6; ++q) {
        P0 *= ((l >> (5 - q)) & 1) ? sx0[q] : cx0[q];
        P1 *= ((l >> (5 - q)) & 1) ? sx1[q] : cx1[q];
    }

    uint32_t v[64];
    v[0] = h2u(__floats2half2_rn(P0 * cx0[11], P1 * cx1[11]));
    v[1] = h2u(__floats2half2_rn(P0 * sx0[11], P1 * sx1[11]));
#pragma unroll
    for (int lvl = 1; lvl < 6; ++lvl) {
        const int q = 11 - lvl;
        const __half2 SX = __floats2half2_rn(sx0[q], sx1[q]);
        const __half2 CX = __floats2half2_rn(cx0[q], cx1[q]);
#pragma unroll
        for (int j = 0; j < (1 << 5); ++j) {
            if (j >= (1 << lvl)) continue;
            v[j + (1 << lvl)] = h2u(__hmul2(u2h(v[j]), SX));
            v[j]              = h2u(__hmul2(u2h(v[j]), CX));
        }
    }

    // pre-loop: stage layer 0's RT1 input
#pragma unroll
    for (int t = 0; t < 16; ++t)
        *(uint4*)&wrow[4 * t] = make_uint4(v[4 * t], v[4 * t + 1], v[4 * t + 2], v[4 * t + 3]);

    float Call = 1.0f;   // product of cos(w/2) over all gates (deferred scale)

    // ---- variational layers ----
#pragma unroll 1
    for (int k = 0; k < DEPTH; ++k) {
        __half2 Tp[NQ], Tn[NQ];
#pragma unroll
        for (int q = 0; q < NQ; ++q) {
            float cw, sw;
            __sincosf(0.5f * W[k * NQ + q], &sw, &cw);
            Call *= cw;
            const float t = sw / cw;
            Tp[q] = __floats2half2_rn(t, t);
            Tn[q] = __floats2half2_rn(-t, -t);
        }

        // ---- RT1 reads fused with shearB<32> (qubit 0) ----
#pragma unroll
        for (int rr = 0; rr < 32; ++rr) {
            const uint32_t* base = (rr & 1) ? colB : colA;
            uint32_t t0 = base[hfun(rr) * LSTRIDE];
            uint32_t t1 = base[(hfun(rr) ^ 0x30) * LSTRIDE];   // hfun(rr+32)=hfun(rr)^0x30
            spair(t0, t1, Tp[0], Tn[0]);
            v[rr]      = t0;
            v[rr + 32] = t1;
        }
        // shearB qubits 1..3 (masks 16,8,4)
        shearv<16>(v, Tp[1], Tn[1]);
        shearv<8>(v, Tp[2], Tn[2]);
        shearv<4>(v, Tp[3], Tn[3]);
        // per-quad: shearB qubits 4,5 (masks 2,1) then RT2-write of that quad
#pragma unroll
        for (int t = 0; t < 16; ++t) {
            spair(v[4 * t],     v[4 * t + 2], Tp[4], Tn[4]);
            spair(v[4 * t + 1], v[4 * t + 3], Tp[4], Tn[4]);
            spair(v[4 * t],     v[4 * t + 1], Tp[5], Tn[5]);
            spair(v[4 * t + 2], v[4 * t + 3], Tp[5], Tn[5]);
            *(uint4*)&wrow[4 * t] = make_uint4(v[4 * t], v[4 * t + 1], v[4 * t + 2], v[4 * t + 3]);
        }

        // ---- RT2 reads fused with shearA<32> (qubit 6) ----
#pragma unroll
        for (int rr = 0; rr < 32; ++rr) {
            uint32_t t0 = rT2[rr * LSTRIDE];
            uint32_t t1 = rT2[(rr + 32) * LSTRIDE];
            spair(t0, t1, Tp[6], Tn[6]);
            v[rr]      = t0;
            v[rr + 32] = t1;
        }
        // shearA qubits 7..9 (masks 16,8,4)
        shearv<16>(v, Tp[7], Tn[7]);
        shearv<8>(v, Tp[8], Tn[8]);
        shearv<4>(v, Tp[9], Tn[9]);
        // per-quad: shearA qubits 10,11 (masks 2,1), then next layer's RT1 write
        if (k < DEPTH - 1) {
#pragma unroll
            for (int t = 0; t < 16; ++t) {
                spair(v[4 * t],     v[4 * t + 2], Tp[10], Tn[10]);
                spair(v[4 * t + 1], v[4 * t + 3], Tp[10], Tn[10]);
                spair(v[4 * t],     v[4 * t + 1], Tp[11], Tn[11]);
                spair(v[4 * t + 2], v[4 * t + 3], Tp[11], Tn[11]);
                *(uint4*)&wrow[4 * t] = make_uint4(v[4 * t], v[4 * t + 1], v[4 * t + 2], v[4 * t + 3]);
            }
        } else {
#pragma unroll
            for (int t = 0; t < 16; ++t) {
                spair(v[4 * t],     v[4 * t + 2], Tp[10], Tn[10]);
                spair(v[4 * t + 1], v[4 * t + 3], Tp[10], Tn[10]);
                spair(v[4 * t],     v[4 * t + 1], Tp[11], Tn[11]);
                spair(v[4 * t + 2], v[4 * t + 3], Tp[11], Tn[11]);
            }
        }
    }

    const float C2 = (Call * Call);   // deferred |amplitude|^2 scale

    // ---- measurement (fp32): <Z_p> per sample, frame A ----
    float c20[16], c21[16];
#pragma unroll
    for (int m = 0; m < 16; ++m) {
        float a0 = 0.0f, a1 = 0.0f;
#pragma unroll
        for (int i = 0; i < 4; ++i) {
            const float2 f = __half22float2(u2h(v[4 * m + i]));
            a0 += f.x * f.x;
            a1 += f.y * f.y;
        }
        c20[m] = a0;
        c21[m] = a1;
    }

    float S0 = 0.0f, S1 = 0.0f;
#pragma unroll
    for (int m = 0; m < 16; ++m) { S0 += c20[m]; S1 += c21[m]; }
    S0 *= C2; S1 *= C2;

    float T0[4], T1[4];
#pragma unroll
    for (int t = 0; t < 4; ++t) {
        float a0 = 0.0f, a1 = 0.0f;
#pragma unroll
        for (int m = 0; m < 16; ++m) {
            const float sgn = ((m >> t) & 1) ? -1.0f : 1.0f;
            a0 += sgn * c20[m];
            a1 += sgn * c21[m];
        }
        T0[t] = a0 * C2;
        T1[t] = a1 * C2;
    }

    float o0[NCLASS], o1[NCLASS];
#pragma unroll
    for (int p = 0; p < 6; ++p) {   // qubit p on lane bit (5-p)
        const float sgn = ((l >> (5 - p)) & 1) ? -1.0f : 1.0f;
        float r0 = sgn * S0, r1 = sgn * S1;
#pragma unroll
        for (int m = 0; m < 6; ++m) { r0 += __shfl_xor(r0, 1 << m, 64); r1 += __shfl_xor(r1, 1 << m, 64); }
        o0[p] = r0; o1[p] = r1;
    }
#pragma unroll
    for (int p = 6; p < 10; ++p) {  // qubit p on reg bit (11-p) -> T[9-p]
        float r0 = T0[9 - p], r1 = T1[9 - p];
#pragma unroll
        for (int m = 0; m < 6; ++m) { r0 += __shfl_xor(r0, 1 << m, 64); r1 += __shfl_xor(r1, 1 << m, 64); }
        o0[p] = r0; o1[p] = r1;
    }

    if (lane == 0) {
#pragma unroll
        for (int p = 0; p < NCLASS; ++p) {
            out[s0 * NCLASS + p] = o0[p];
            out[s1 * NCLASS + p] = o1[p];
        }
    }
}

extern "C" void kernel_launch(void* const* d_in, const int* in_sizes, int n_in,
                              void* d_out, int out_size, void* d_ws, size_t ws_size,
                              hipStream_t stream) {
    const float* X = (const float*)d_in[0];
    const float* W = (const float*)d_in[1];
    float* out     = (float*)d_out;
    (void)in_sizes; (void)n_in; (void)out_size; (void)d_ws; (void)ws_size;

    dim3 grid(BATCH / (2 * WPB));   // 2 samples per wave, WPB waves per block
    dim3 block(WPB * 64);
    hipLaunchKernelGGL(vqc_kernel, grid, block, 0, stream, X, W, out);
}

// Round 10
// 97.182 us; speedup vs baseline: 1.0170x; 1.0170x over previous
//
#include <hip/hip_runtime.h>
#include <hip/hip_fp16.h>

#define NQ 12
#define DEPTH 8
#define NCLASS 10
#define BATCH 4096
#define LSTRIDE 68   // LDS row stride in DWORDS (272 B; 16B-aligned rows; bank phase 4l -> <=2-way)
#define WPB 2        // waves per block; 2 samples/wave; LDS = 2*64*68*4 = 34816 B

// ---------------------------------------------------------------------------
// One wave per TWO samples; amplitude pair packed as __half2 in v[64] dwords.
// Frame A: qubit q in 0..5  <-> lane bit (5-q);  q in 6..11 <-> reg bit (11-q)
// Frame B: qubit q in 0..5  <-> reg  bit (5-q);  q in 6..11 <-> lane bit (11-q)
// R10 = R8 program order (R9's read/shear fusion regressed) + ds_read2_b32
// pairing of the RT reads:
//   RT1: pairs (r, r|2): hfun(r^2)=hfun(r)^3 -> same column base, row delta
//        <= 3*68 = 204 dwords <= 255 -> per-pair base + two small immediates
//   RT2: pairs (j, j+1): offsets {0, 68} dwords from per-pair base
// Shears use tan-half-angle form; global cos product deferred to epilogue.
// All DS intra-wave (private region per wave, DS in-order) -> no barriers.
// ---------------------------------------------------------------------------

__device__ __forceinline__ uint32_t h2u(__half2 x) { return __builtin_bit_cast(uint32_t, x); }
__device__ __forceinline__ __half2 u2h(uint32_t x) { return __builtin_bit_cast(__half2, x); }

__device__ constexpr int hfun(int r) {  // src row (old lane) for RT1 output reg r
    const int rb5 = (r >> 5) & 1, rb4 = (r >> 4) & 1, rb3 = (r >> 3) & 1;
    const int rb2 = (r >> 2) & 1, rb1 = (r >> 1) & 1, rb0 = r & 1;
    const int c0 = rb5;
    const int c1 = rb4 ^ rb5;
    const int c2 = rb3 ^ rb4;
    const int c3 = rb2 ^ rb3 ^ rb4;
    const int c4 = rb1 ^ rb2;
    const int c5 = rb0 ^ rb1 ^ rb2;
    return (c0 << 5) | (c1 << 4) | (c2 << 3) | (c3 << 2) | (c4 << 1) | c5;
}

// shear pair: a' = a - t*b ; b' = b + t*a  (tan half-angle form)
__device__ __forceinline__ void spair(uint32_t& a_, uint32_t& b_, __half2 Tp, __half2 Tn) {
    const __half2 a = u2h(a_), b = u2h(b_);
    a_ = h2u(__hfma2(Tn, b, a));
    b_ = h2u(__hfma2(Tp, a, b));
}

template <int M>
__device__ __forceinline__ void shearv(uint32_t (&v)[64], __half2 Tp, __half2 Tn) {
#pragma unroll
    for (int r = 0; r < 64; ++r) {
        if (r & M) continue;
        spair(v[r], v[r | M], Tp, Tn);
    }
}

__global__ __launch_bounds__(WPB * 64) void vqc_kernel(const float* __restrict__ X,
                                                       const float* __restrict__ W,
                                                       float* __restrict__ out) {
    __shared__ __align__(16) uint32_t lds[WPB * 64 * LSTRIDE];

    const int lane = threadIdx.x & 63;
    const int wid  = threadIdx.x >> 6;
    const int gw   = blockIdx.x * WPB + wid;   // global wave id
    const int s0   = 2 * gw, s1 = s0 + 1;      // the two samples
    const int l    = lane;

    uint32_t* Wb   = &lds[wid * 64 * LSTRIDE];
    uint32_t* wrow = &Wb[l * LSTRIDE];                 // staging write base (16B aligned)
    const int G = l ^ (l >> 1) ^ ((l >> 2) & 5);       // RT1 src col (lane-local CNOTs folded)
    const uint32_t* colA = &Wb[G];                     // r even (q5=0)
    const uint32_t* colB = &Wb[G ^ 0x30];              // r odd  (q5=1): CNOT(5,6) col flip
    const uint32_t* rT2  = &Wb[l];                     // RT2 read base

    // ---- data encoding: product state for both samples, frame A ----
    float cx0[NQ], sx0[NQ], cx1[NQ], sx1[NQ];
#pragma unroll
    for (int q = 0; q < NQ; ++q) {
        __sincosf(0.5f * X[s0 * NQ + q] + 0.78539816339744831f, &sx0[q], &cx0[q]);
        __sincosf(0.5f * X[s1 * NQ + q] + 0.78539816339744831f, &sx1[q], &cx1[q]);
    }
    float P0 = 1.0f, P1 = 1.0f;
#pragma unroll
    for (int q = 0; q < 6; ++q) {
        P0 *= ((l >> (5 - q)) & 1) ? sx0[q] : cx0[q];
        P1 *= ((l >> (5 - q)) & 1) ? sx1[q] : cx1[q];
    }

    uint32_t v[64];
    v[0] = h2u(__floats2half2_rn(P0 * cx0[11], P1 * cx1[11]));
    v[1] = h2u(__floats2half2_rn(P0 * sx0[11], P1 * sx1[11]));
#pragma unroll
    for (int lvl = 1; lvl < 6; ++lvl) {
        const int q = 11 - lvl;
        const __half2 SX = __floats2half2_rn(sx0[q], sx1[q]);
        const __half2 CX = __floats2half2_rn(cx0[q], cx1[q]);
#pragma unroll
        for (int j = 0; j < (1 << 5); ++j) {
            if (j >= (1 << lvl)) continue;
            v[j + (1 << lvl)] = h2u(__hmul2(u2h(v[j]), SX));
            v[j]              = h2u(__hmul2(u2h(v[j]), CX));
        }
    }

    float Call = 1.0f;   // product of cos(w/2) over all gates (deferred scale)

    // ---- variational layers ----
#pragma unroll 1
    for (int k = 0; k < DEPTH; ++k) {
        __half2 Tp[NQ], Tn[NQ];
#pragma unroll
        for (int q = 0; q < NQ; ++q) {
            float cw, sw;
            __sincosf(0.5f * W[k * NQ + q], &sw, &cw);
            Call *= cw;
            const float t = sw / cw;
            Tp[q] = __floats2half2_rn(t, t);
            Tn[q] = __floats2half2_rn(-t, -t);
        }

        // ---- RT1 write: frame A rows, b128 ----
#pragma unroll
        for (int t = 0; t < 16; ++t)
            *(uint4*)&wrow[4 * t] = make_uint4(v[4 * t], v[4 * t + 1], v[4 * t + 2], v[4 * t + 3]);

        // ---- RT1 reads: pairs (r, r|2) -> ds_read2_b32 (row delta <= 204 dw) ----
#pragma unroll
        for (int m = 0; m < 32; ++m) {
            const int r  = ((m >> 1) << 2) | (m & 1);   // r with bit1 == 0
            const int ha = hfun(r);
            const int hb = ha ^ 3;                      // hfun(r|2)
            const int h0 = (ha < hb) ? ha : hb;
            const uint32_t* base = ((r & 1) ? colB : colA) + h0 * LSTRIDE;
            v[r]     = base[(ha - h0) * LSTRIDE];
            v[r | 2] = base[(hb - h0) * LSTRIDE];
        }

        // ---- shear-RY qubits 0..5 (frame B: qubit p <-> reg bit 5-p) ----
        shearv<32>(v, Tp[0], Tn[0]);
        shearv<16>(v, Tp[1], Tn[1]);
        shearv<8>(v, Tp[2], Tn[2]);
        shearv<4>(v, Tp[3], Tn[3]);
        shearv<2>(v, Tp[4], Tn[4]);
        shearv<1>(v, Tp[5], Tn[5]);

        // ---- RT2 write: frame B rows, b128 ----
#pragma unroll
        for (int t = 0; t < 16; ++t)
            *(uint4*)&wrow[4 * t] = make_uint4(v[4 * t], v[4 * t + 1], v[4 * t + 2], v[4 * t + 3]);

        // ---- RT2 reads: pairs (j, j+1) -> ds_read2_b32 (offsets {0,68} dw) ----
#pragma unroll
        for (int m = 0; m < 32; ++m) {
            const uint32_t* base = rT2 + (2 * m) * LSTRIDE;
            v[2 * m]     = base[0];
            v[2 * m + 1] = base[LSTRIDE];
        }

        // ---- shear-RY qubits 6..11 (frame A: qubit p <-> reg bit 11-p) ----
        shearv<32>(v, Tp[6], Tn[6]);
        shearv<16>(v, Tp[7], Tn[7]);
        shearv<8>(v, Tp[8], Tn[8]);
        shearv<4>(v, Tp[9], Tn[9]);
        shearv<2>(v, Tp[10], Tn[10]);
        shearv<1>(v, Tp[11], Tn[11]);
    }

    const float C2 = (Call * Call);   // deferred |amplitude|^2 scale

    // ---- measurement (fp32): <Z_p> per sample, frame A ----
    float c20[16], c21[16];
#pragma unroll
    for (int m = 0; m < 16; ++m) {
        float a0 = 0.0f, a1 = 0.0f;
#pragma unroll
        for (int i = 0; i < 4; ++i) {
            const float2 f = __half22float2(u2h(v[4 * m + i]));
            a0 += f.x * f.x;
            a1 += f.y * f.y;
        }
        c20[m] = a0;
        c21[m] = a1;
    }

    float S0 = 0.0f, S1 = 0.0f;
#pragma unroll
    for (int m = 0; m < 16; ++m) { S0 += c20[m]; S1 += c21[m]; }
    S0 *= C2; S1 *= C2;

    float T0[4], T1[4];
#pragma unroll
    for (int t = 0; t < 4; ++t) {
        float a0 = 0.0f, a1 = 0.0f;
#pragma unroll
        for (int m = 0; m < 16; ++m) {
            const float sgn = ((m >> t) & 1) ? -1.0f : 1.0f;
            a0 += sgn * c20[m];
            a1 += sgn * c21[m];
        }
        T0[t] = a0 * C2;
        T1[t] = a1 * C2;
    }

    float o0[NCLASS], o1[NCLASS];
#pragma unroll
    for (int p = 0; p < 6; ++p) {   // qubit p on lane bit (5-p)
        const float sgn = ((l >> (5 - p)) & 1) ? -1.0f : 1.0f;
        float r0 = sgn * S0, r1 = sgn * S1;
#pragma unroll
        for (int m = 0; m < 6; ++m) { r0 += __shfl_xor(r0, 1 << m, 64); r1 += __shfl_xor(r1, 1 << m, 64); }
        o0[p] = r0; o1[p] = r1;
    }
#pragma unroll
    for (int p = 6; p < 10; ++p) {  // qubit p on reg bit (11-p) -> T[9-p]
        float r0 = T0[9 - p], r1 = T1[9 - p];
#pragma unroll
        for (int m = 0; m < 6; ++m) { r0 += __shfl_xor(r0, 1 << m, 64); r1 += __shfl_xor(r1, 1 << m, 64); }
        o0[p] = r0; o1[p] = r1;
    }

    if (lane == 0) {
#pragma unroll
        for (int p = 0; p < NCLASS; ++p) {
            out[s0 * NCLASS + p] = o0[p];
            out[s1 * NCLASS + p] = o1[p];
        }
    }
}

extern "C" void kernel_launch(void* const* d_in, const int* in_sizes, int n_in,
                              void* d_out, int out_size, void* d_ws, size_t ws_size,
                              hipStream_t stream) {
    const float* X = (const float*)d_in[0];
    const float* W = (const float*)d_in[1];
    float* out     = (float*)d_out;
    (void)in_sizes; (void)n_in; (void)out_size; (void)d_ws; (void)ws_size;

    dim3 grid(BATCH / (2 * WPB));   // 2 samples per wave, WPB waves per block
    dim3 block(WPB * 64);
    hipLaunchKernelGGL(vqc_kernel, grid, block, 0, stream, X, W, out);
}